// Round 6
// baseline (349.876 us; speedup 1.0000x reference)
//
#include <hip/hip_runtime.h>
#include <hip/hip_fp16.h>
#include <stdint.h>
#include <stddef.h>

#define C_INC 320
#define KREAL 2880
#define KPAD  2944
#define OUT_F 384
#define RANK  32
#define HH    64
#define WW    64
#define NTOK  16384
#define NCH   16         // channel chunks for fused kernel
#define CCH   20         // channels per chunk (16*20=320)
#define QSTR  76         // qbuf row stride bytes (max 8ch*9=72 +4 pad)
#define USTR  36         // rs/upn LDS row stride (floats): 16B-aligned, 2-way-conflict max

typedef int vi4 __attribute__((ext_vector_type(4)));

// ---------------- quantize weights per output row (exact IEEE div) ----------------
__global__ __launch_bounds__(256) void kq_w(const float* __restrict__ w,
                                            int8_t* __restrict__ qw,
                                            float* __restrict__ sw) {
    int o = blockIdx.x;
    const float* row = w + (size_t)o * KPAD;
    float m = 0.f;
    for (int k = threadIdx.x; k < KPAD; k += 256) m = fmaxf(m, fabsf(row[k]));
    #pragma unroll
    for (int off = 32; off > 0; off >>= 1) m = fmaxf(m, __shfl_down(m, off, 64));
    __shared__ float red[4];
    __shared__ float sval;
    if ((threadIdx.x & 63) == 0) red[threadIdx.x >> 6] = m;
    __syncthreads();
    if (threadIdx.x == 0) {
        float mm = fmaxf(fmaxf(red[0], red[1]), fmaxf(red[2], red[3]));
        sval = fmaxf(mm / 7.0f, 1e-8f);
        sw[o] = sval;
    }
    __syncthreads();
    float s = sval;
    for (int k = threadIdx.x; k < KPAD; k += 256) {
        float q = rintf(row[k] / s);          // IEEE div + RNE, matches np
        q = fminf(fmaxf(q, -8.f), 7.f);
        qw[(size_t)o * KPAD + k] = (int8_t)q;
    }
}

// ---------------- per-pixel channel abs-max, channel-split (512 blocks) ----------------
__global__ __launch_bounds__(256) void k_chmax(const float* __restrict__ x,
                                               float* __restrict__ mb2) {
    int p = blockIdx.x * 256 + threadIdx.x;   // 0..16383
    int cc = blockIdx.y;                       // 0..7
    int n = p >> 12, hw = p & 4095;
    const float* base = x + ((size_t)(n * C_INC) + cc * 40) * 4096 + hw;
    float m = 0.f;
    #pragma unroll 4
    for (int c = 0; c < 40; ++c) m = fmaxf(m, fabsf(base[(size_t)c * 4096]));
    mb2[(size_t)cc * NTOK + p] = m;
}

// ---------------- sx = max over 3x3 neighborhood of 8 planes / 7 ----------------
__global__ __launch_bounds__(256) void k_sx(const float* __restrict__ mb2,
                                            float* __restrict__ sx) {
    int p = blockIdx.x * 256 + threadIdx.x;
    int n = p >> 12, hw = p & 4095;
    int h = hw >> 6, w = hw & 63;
    float m = 0.f;
    #pragma unroll
    for (int cc = 0; cc < 8; ++cc) {
        const float* pl = mb2 + (size_t)cc * NTOK + (n << 12);
        #pragma unroll
        for (int di = -1; di <= 1; ++di)
            #pragma unroll
            for (int dj = -1; dj <= 1; ++dj) {
                int hh = h + di, ww = w + dj;
                if ((unsigned)hh < (unsigned)HH && (unsigned)ww < (unsigned)WW)
                    m = fmaxf(m, pl[(hh << 6) + ww]);
            }
    }
    sx[p] = fmaxf(m / 7.0f, 1e-8f);
}

// ---------------- fused im2col quantize + LoRA down-projection ----------------
// grid (128, 16), block 128 thr (2 waves = 2 image rows). One wave per row
// (lane = w); neighbors via direct predicated global loads (no shfl — R4).
// 3 phases of {8,8,4} channels, per-phase pdl staging. LDS 18.9 KB ->
// 8 blocks/CU; grid 2048 = 8/CU for finer XCD balance.
__global__ __launch_bounds__(128) void k_fused(const float* __restrict__ x,
                                               const float* __restrict__ pd,
                                               const float* __restrict__ sx,
                                               int8_t* __restrict__ qx,
                                               __half* __restrict__ rpart) {
    __shared__ float  pdl[8 * 9 * RANK];   // 9216 B (max phase: 8 channels)
    __shared__ int8_t qbuf[128 * QSTR];    // 9728 B
    const int pstart[4] = {0, 8, 16, 20};  // phase channel starts (sizes 8,8,4)
    const int phoff[3]  = {0, 72, 144};    // byte offset within this chunk's k-range

    int tid = threadIdx.x;                 // 0..127
    int rg = blockIdx.x;                   // 0..127
    int cc = blockIdx.y;                   // 0..15
    int n = rg >> 5, h4 = rg & 31;         // h4 = row-pair index
    int wid = tid >> 6, lane = tid & 63;
    int h = h4 * 2 + wid;
    int c0 = cc * CCH;

    int t = (n << 12) + (h << 6) + lane;
    float s = sx[t];
    float inv = 1.0f / s;                  // one exact div per lane
    const float* xrow = x + ((size_t)(n * C_INC) + c0) * 4096 + (h << 6) + lane;
    bool hok0 = (h > 0), hok2 = (h < 63);
    bool wok0 = (lane > 0), wok2 = (lane < 63);
    int bt = (n << 12) + (h4 << 7);        // block's first token

    float acc[RANK];
    #pragma unroll
    for (int j = 0; j < RANK; ++j) acc[j] = 0.f;

    for (int ph = 0; ph < 3; ++ph) {
        int ps = pstart[ph], pch = pstart[ph + 1] - ps;
        __syncthreads();   // prior phase's pdl reads + qbuf writes complete
        if (ph > 0) {      // flush previous phase (8 ch = 18 dwords/row)
            for (int i = tid; i < 128 * 18; i += 128) {
                int row = i / 18, col = i - row * 18;
                *(unsigned int*)&qx[(size_t)(bt + row) * KPAD + cc * 180 + phoff[ph - 1] + col * 4] =
                    *(unsigned int*)&qbuf[row * QSTR + col * 4];
            }
        }
        for (int i = tid; i < pch * 9 * RANK; i += 128)
            pdl[i] = pd[((size_t)(c0 + ps) * 9) * RANK + i];
        __syncthreads();   // pdl ready, flush done

        for (int cl = 0; cl < pch; ++cl) {
            const float* xc = xrow + (size_t)(ps + cl) * 4096;
            float v[9];
            v[0] = (hok0 && wok0) ? xc[-65] : 0.f;
            v[1] =  hok0          ? xc[-64] : 0.f;
            v[2] = (hok0 && wok2) ? xc[-63] : 0.f;
            v[3] =  wok0          ? xc[-1]  : 0.f;
            v[4] =                  xc[0];
            v[5] =  wok2          ? xc[1]   : 0.f;
            v[6] = (hok2 && wok0) ? xc[63]  : 0.f;
            v[7] =  hok2          ? xc[64]  : 0.f;
            v[8] = (hok2 && wok2) ? xc[65]  : 0.f;
            #pragma unroll
            for (int u = 0; u < 9; ++u) {
                float q = rintf(v[u] * inv);
                q = fminf(fmaxf(q, -8.f), 7.f);
                qbuf[tid * QSTR + cl * 9 + u] = (int8_t)q;
                const float4* p4 = (const float4*)&pdl[(cl * 9 + u) * RANK];
                #pragma unroll
                for (int jj = 0; jj < 8; ++jj) {
                    float4 pv = p4[jj];
                    acc[jj * 4 + 0] = fmaf(v[u], pv.x, acc[jj * 4 + 0]);
                    acc[jj * 4 + 1] = fmaf(v[u], pv.y, acc[jj * 4 + 1]);
                    acc[jj * 4 + 2] = fmaf(v[u], pv.z, acc[jj * 4 + 2]);
                    acc[jj * 4 + 3] = fmaf(v[u], pv.w, acc[jj * 4 + 3]);
                }
            }
        }
    }

    // store rpart partials as fp16
    {
        union { __half hh[RANK]; uint4 u4[4]; } pk;
        #pragma unroll
        for (int j = 0; j < RANK; ++j) pk.hh[j] = __float2half_rn(acc[j]);
        uint4* rp = (uint4*)(rpart + ((size_t)cc * NTOK + t) * RANK);
        rp[0] = pk.u4[0]; rp[1] = pk.u4[1]; rp[2] = pk.u4[2]; rp[3] = pk.u4[3];
    }

    // flush phase 2 (4 ch = 9 dwords; cc==15 adds 16 zero dwords for k-pad)
    __syncthreads();
    if (cc == NCH - 1) {
        for (int i = tid; i < 128 * 25; i += 128) {
            int row = i / 25, col = i - row * 25;
            unsigned int vdw = (col < 9) ? *(unsigned int*)&qbuf[row * QSTR + col * 4] : 0u;
            *(unsigned int*)&qx[(size_t)(bt + row) * KPAD + cc * 180 + 144 + col * 4] = vdw;
        }
    } else {
        for (int i = tid; i < 128 * 9; i += 128) {
            int row = i / 9, col = i - row * 9;
            *(unsigned int*)&qx[(size_t)(bt + row) * KPAD + cc * 180 + 144 + col * 4] =
                *(unsigned int*)&qbuf[row * QSTR + col * 4];
        }
    }
}

// ---------------- int8 MFMA GEMM + fused lora/bias epilogue ----------------
// grid (3, 128): blockIdx.x = n-tile (fast dim) so the 3 n-tiles sharing one
// qx m-tile dispatch adjacently -> L2/L3 reuse. Epilogue adds
// (sum_cc rpart) @ up + bias directly: k_epi pass (25 MB read + 25 MB write)
// eliminated.
__global__ __launch_bounds__(256) void k_gemm(const int8_t* __restrict__ qx,
                                              const int8_t* __restrict__ qw,
                                              const float* __restrict__ sx,
                                              const float* __restrict__ sw,
                                              const __half* __restrict__ rpart,
                                              const float* __restrict__ up,
                                              const float* __restrict__ bias,
                                              float* __restrict__ out) {
    __shared__ int8_t lsA[128 * 80];       // 10240 B
    __shared__ int8_t lsB[128 * 80];       // 10240 B
    __shared__ float  rs[128 * USTR];      // 18432 B: summed rpart for block's tokens
    __shared__ float  upn[128 * USTR];     // 18432 B: up[:, n0:n0+128] transposed
    int tid = threadIdx.x;
    int m0 = blockIdx.y * 128;
    int n0 = blockIdx.x * 128;
    int wid = tid >> 6, lane = tid & 63;
    int wr = wid >> 1, wc = wid & 1;
    int lg = lane >> 4, lr = lane & 15;

    // stage rs = sum over 16 chunks of rpart (fp16 -> fp32)
    for (int i = tid; i < 128 * RANK; i += 256) {
        int tt = i >> 5, j = i & 31;
        float ssum = 0.f;
        #pragma unroll
        for (int cc = 0; cc < NCH; ++cc)
            ssum += __half2float(rpart[((size_t)cc * NTOK + m0 + tt) * RANK + j]);
        rs[tt * USTR + j] = ssum;
    }
    // stage upn[col][j] = up[j][n0+col]  (transposed for contiguous per-col dot)
    for (int i = tid; i < 128 * RANK; i += 256) {
        int col = i & 127, j = i >> 7;
        upn[col * USTR + j] = up[(size_t)j * OUT_F + n0 + col];
    }

    vi4 acc[4][4];
    #pragma unroll
    for (int i = 0; i < 4; ++i)
        #pragma unroll
        for (int j = 0; j < 4; ++j) acc[i][j] = (vi4)0;

    for (int kk = 0; kk < KPAD; kk += 64) {
        #pragma unroll
        for (int i = 0; i < 2; ++i) {
            int chunk = tid + i * 256;        // 0..511 chunks of 16B
            int row = chunk >> 2, c4 = chunk & 3;
            *(vi4*)&lsA[row * 80 + c4 * 16] =
                *(const vi4*)&qx[(size_t)(m0 + row) * KPAD + kk + c4 * 16];
            *(vi4*)&lsB[row * 80 + c4 * 16] =
                *(const vi4*)&qw[(size_t)(n0 + row) * KPAD + kk + c4 * 16];
        }
        __syncthreads();                      // also covers rs/upn staging (1st iter)
        vi4 af[4], bf[4];
        #pragma unroll
        for (int mi = 0; mi < 4; ++mi)
            af[mi] = *(vi4*)&lsA[(wr * 64 + mi * 16 + lr) * 80 + lg * 16];
        #pragma unroll
        for (int ni = 0; ni < 4; ++ni)
            bf[ni] = *(vi4*)&lsB[(wc * 64 + ni * 16 + lr) * 80 + lg * 16];
        #pragma unroll
        for (int mi = 0; mi < 4; ++mi)
            #pragma unroll
            for (int ni = 0; ni < 4; ++ni)
                acc[mi][ni] = __builtin_amdgcn_mfma_i32_16x16x64_i8(af[mi], bf[ni], acc[mi][ni], 0, 0, 0);
        __syncthreads();
    }

    float swv[4], bv[4];
    #pragma unroll
    for (int ni = 0; ni < 4; ++ni) {
        int colr = wc * 64 + ni * 16 + lr;
        swv[ni] = sw[n0 + colr];
        bv[ni]  = bias[n0 + colr];
    }
    #pragma unroll
    for (int mi = 0; mi < 4; ++mi) {
        int rbase = wr * 64 + mi * 16 + lg * 4;    // block-relative row
        #pragma unroll
        for (int r = 0; r < 4; ++r) {
            int rowr = rbase + r;
            float sxv = sx[m0 + rowr];
            const float* rrow = &rs[rowr * USTR];
            #pragma unroll
            for (int ni = 0; ni < 4; ++ni) {
                int colr = wc * 64 + ni * 16 + lr;
                const float* ucol = &upn[colr * USTR];
                float l = 0.f;
                #pragma unroll
                for (int j = 0; j < RANK; ++j) l = fmaf(rrow[j], ucol[j], l);
                out[(size_t)(m0 + rowr) * OUT_F + n0 + colr] =
                    ((float)acc[mi][ni][r] * sxv) * swv[ni] + l + bv[ni];
            }
        }
    }
}

extern "C" void kernel_launch(void* const* d_in, const int* in_sizes, int n_in,
                              void* d_out, int out_size, void* d_ws, size_t ws_size,
                              hipStream_t stream) {
    const float* x    = (const float*)d_in[0];
    const float* w    = (const float*)d_in[1];
    const float* pd   = (const float*)d_in[2];
    const float* pu   = (const float*)d_in[3];
    const float* bias = (const float*)d_in[4];
    float* out = (float*)d_out;

    char* ws = (char*)d_ws;
    int8_t* qw    = (int8_t*)(ws + 0);           // 1,130,496
    float*  sw    = (float*) (ws + 1130496);     // 1,536
    float*  mb2   = (float*) (ws + 1132032);     // 8*16384*4 = 524,288
    float*  sx    = (float*) (ws + 1656320);     // 65,536
    int8_t* qx    = (int8_t*)(ws + 1721856);     // 48,234,496
    __half* rpart = (__half*)(ws + 49956352);    // 16*16384*32*2 = 16,777,216 (end 66,733,568)

    hipLaunchKernelGGL(kq_w,    dim3(OUT_F),    dim3(256), 0, stream, w, qw, sw);
    hipLaunchKernelGGL(k_chmax, dim3(64, 8),    dim3(256), 0, stream, x, mb2);
    hipLaunchKernelGGL(k_sx,    dim3(64),       dim3(256), 0, stream, mb2, sx);
    hipLaunchKernelGGL(k_fused, dim3(128, NCH), dim3(128), 0, stream, x, pd, sx, qx, rpart);
    hipLaunchKernelGGL(k_gemm,  dim3(3, 128),   dim3(256), 0, stream, qx, qw, sx, sw,
                       rpart, pu, bias, out);
}

// Round 7
// 248.762 us; speedup vs baseline: 1.4065x; 1.4065x over previous
//
#include <hip/hip_runtime.h>
#include <hip/hip_fp16.h>
#include <stdint.h>
#include <stddef.h>

#define C_INC 320
#define KREAL 2880
#define KPAD  2944
#define OUT_F 384
#define RANK  32
#define HH    64
#define WW    64
#define NTOK  16384
#define NCH   16         // channel chunks for fused kernel
#define CCH   20         // channels per chunk (16*20=320)
#define QSTR  76         // qbuf row stride bytes (max 8ch*9=72 +4 pad)

typedef int vi4 __attribute__((ext_vector_type(4)));

// async global->LDS, 16B per lane; LDS dest is wave-uniform base + lane*16
static __device__ __forceinline__ void async16(const void* g, void* l) {
    __builtin_amdgcn_global_load_lds(
        (const __attribute__((address_space(1))) unsigned int*)g,
        (__attribute__((address_space(3))) unsigned int*)l, 16, 0, 0);
}

// ---------------- quantize weights per output row (exact IEEE div) ----------------
__global__ __launch_bounds__(256) void kq_w(const float* __restrict__ w,
                                            int8_t* __restrict__ qw,
                                            float* __restrict__ sw) {
    int o = blockIdx.x;
    const float* row = w + (size_t)o * KPAD;
    float m = 0.f;
    for (int k = threadIdx.x; k < KPAD; k += 256) m = fmaxf(m, fabsf(row[k]));
    #pragma unroll
    for (int off = 32; off > 0; off >>= 1) m = fmaxf(m, __shfl_down(m, off, 64));
    __shared__ float red[4];
    __shared__ float sval;
    if ((threadIdx.x & 63) == 0) red[threadIdx.x >> 6] = m;
    __syncthreads();
    if (threadIdx.x == 0) {
        float mm = fmaxf(fmaxf(red[0], red[1]), fmaxf(red[2], red[3]));
        sval = fmaxf(mm / 7.0f, 1e-8f);
        sw[o] = sval;
    }
    __syncthreads();
    float s = sval;
    for (int k = threadIdx.x; k < KPAD; k += 256) {
        float q = rintf(row[k] / s);          // IEEE div + RNE, matches np
        q = fminf(fmaxf(q, -8.f), 7.f);
        qw[(size_t)o * KPAD + k] = (int8_t)q;
    }
}

// ---------------- per-pixel channel abs-max, channel-split (512 blocks) ----------------
__global__ __launch_bounds__(256) void k_chmax(const float* __restrict__ x,
                                               float* __restrict__ mb2) {
    int p = blockIdx.x * 256 + threadIdx.x;   // 0..16383
    int cc = blockIdx.y;                       // 0..7
    int n = p >> 12, hw = p & 4095;
    const float* base = x + ((size_t)(n * C_INC) + cc * 40) * 4096 + hw;
    float m = 0.f;
    #pragma unroll 4
    for (int c = 0; c < 40; ++c) m = fmaxf(m, fabsf(base[(size_t)c * 4096]));
    mb2[(size_t)cc * NTOK + p] = m;
}

// ---------------- sx = max over 3x3 neighborhood of 8 planes / 7 ----------------
__global__ __launch_bounds__(256) void k_sx(const float* __restrict__ mb2,
                                            float* __restrict__ sx) {
    int p = blockIdx.x * 256 + threadIdx.x;
    int n = p >> 12, hw = p & 4095;
    int h = hw >> 6, w = hw & 63;
    float m = 0.f;
    #pragma unroll
    for (int cc = 0; cc < 8; ++cc) {
        const float* pl = mb2 + (size_t)cc * NTOK + (n << 12);
        #pragma unroll
        for (int di = -1; di <= 1; ++di)
            #pragma unroll
            for (int dj = -1; dj <= 1; ++dj) {
                int hh = h + di, ww = w + dj;
                if ((unsigned)hh < (unsigned)HH && (unsigned)ww < (unsigned)WW)
                    m = fmaxf(m, pl[(hh << 6) + ww]);
            }
    }
    sx[p] = fmaxf(m / 7.0f, 1e-8f);
}

// ---------------- fused im2col quantize + LoRA down-projection (R6 verbatim) ----------------
__global__ __launch_bounds__(128) void k_fused(const float* __restrict__ x,
                                               const float* __restrict__ pd,
                                               const float* __restrict__ sx,
                                               int8_t* __restrict__ qx,
                                               __half* __restrict__ rpart) {
    __shared__ float  pdl[8 * 9 * RANK];   // 9216 B (max phase: 8 channels)
    __shared__ int8_t qbuf[128 * QSTR];    // 9728 B
    const int pstart[4] = {0, 8, 16, 20};  // phase channel starts (sizes 8,8,4)
    const int phoff[3]  = {0, 72, 144};    // byte offset within this chunk's k-range

    int tid = threadIdx.x;                 // 0..127
    int rg = blockIdx.x;                   // 0..127
    int cc = blockIdx.y;                   // 0..15
    int n = rg >> 5, h4 = rg & 31;         // h4 = row-pair index
    int wid = tid >> 6, lane = tid & 63;
    int h = h4 * 2 + wid;
    int c0 = cc * CCH;

    int t = (n << 12) + (h << 6) + lane;
    float s = sx[t];
    float inv = 1.0f / s;                  // one exact div per lane
    const float* xrow = x + ((size_t)(n * C_INC) + c0) * 4096 + (h << 6) + lane;
    bool hok0 = (h > 0), hok2 = (h < 63);
    bool wok0 = (lane > 0), wok2 = (lane < 63);
    int bt = (n << 12) + (h4 << 7);        // block's first token

    float acc[RANK];
    #pragma unroll
    for (int j = 0; j < RANK; ++j) acc[j] = 0.f;

    for (int ph = 0; ph < 3; ++ph) {
        int ps = pstart[ph], pch = pstart[ph + 1] - ps;
        __syncthreads();   // prior phase's pdl reads + qbuf writes complete
        if (ph > 0) {      // flush previous phase (8 ch = 18 dwords/row)
            for (int i = tid; i < 128 * 18; i += 128) {
                int row = i / 18, col = i - row * 18;
                *(unsigned int*)&qx[(size_t)(bt + row) * KPAD + cc * 180 + phoff[ph - 1] + col * 4] =
                    *(unsigned int*)&qbuf[row * QSTR + col * 4];
            }
        }
        for (int i = tid; i < pch * 9 * RANK; i += 128)
            pdl[i] = pd[((size_t)(c0 + ps) * 9) * RANK + i];
        __syncthreads();   // pdl ready, flush done

        for (int cl = 0; cl < pch; ++cl) {
            const float* xc = xrow + (size_t)(ps + cl) * 4096;
            float v[9];
            v[0] = (hok0 && wok0) ? xc[-65] : 0.f;
            v[1] =  hok0          ? xc[-64] : 0.f;
            v[2] = (hok0 && wok2) ? xc[-63] : 0.f;
            v[3] =  wok0          ? xc[-1]  : 0.f;
            v[4] =                  xc[0];
            v[5] =  wok2          ? xc[1]   : 0.f;
            v[6] = (hok2 && wok0) ? xc[63]  : 0.f;
            v[7] =  hok2          ? xc[64]  : 0.f;
            v[8] = (hok2 && wok2) ? xc[65]  : 0.f;
            #pragma unroll
            for (int u = 0; u < 9; ++u) {
                float q = rintf(v[u] * inv);
                q = fminf(fmaxf(q, -8.f), 7.f);
                qbuf[tid * QSTR + cl * 9 + u] = (int8_t)q;
                const float4* p4 = (const float4*)&pdl[(cl * 9 + u) * RANK];
                #pragma unroll
                for (int jj = 0; jj < 8; ++jj) {
                    float4 pv = p4[jj];
                    acc[jj * 4 + 0] = fmaf(v[u], pv.x, acc[jj * 4 + 0]);
                    acc[jj * 4 + 1] = fmaf(v[u], pv.y, acc[jj * 4 + 1]);
                    acc[jj * 4 + 2] = fmaf(v[u], pv.z, acc[jj * 4 + 2]);
                    acc[jj * 4 + 3] = fmaf(v[u], pv.w, acc[jj * 4 + 3]);
                }
            }
        }
    }

    // store rpart partials as fp16
    {
        union { __half hh[RANK]; uint4 u4[4]; } pk;
        #pragma unroll
        for (int j = 0; j < RANK; ++j) pk.hh[j] = __float2half_rn(acc[j]);
        uint4* rp = (uint4*)(rpart + ((size_t)cc * NTOK + t) * RANK);
        rp[0] = pk.u4[0]; rp[1] = pk.u4[1]; rp[2] = pk.u4[2]; rp[3] = pk.u4[3];
    }

    // flush phase 2 (4 ch = 9 dwords; cc==15 adds 16 zero dwords for k-pad)
    __syncthreads();
    if (cc == NCH - 1) {
        for (int i = tid; i < 128 * 25; i += 128) {
            int row = i / 25, col = i - row * 25;
            unsigned int vdw = (col < 9) ? *(unsigned int*)&qbuf[row * QSTR + col * 4] : 0u;
            *(unsigned int*)&qx[(size_t)(bt + row) * KPAD + cc * 180 + 144 + col * 4] = vdw;
        }
    } else {
        for (int i = tid; i < 128 * 9; i += 128) {
            int row = i / 9, col = i - row * 9;
            *(unsigned int*)&qx[(size_t)(bt + row) * KPAD + cc * 180 + 144 + col * 4] =
                *(unsigned int*)&qbuf[row * QSTR + col * 4];
        }
    }
}

// ---------------- int8 MFMA GEMM: 64x128 tiles, async global->LDS staging ----------------
// grid (3, 256) = 768 blocks = exactly 3/CU. LDS rows unpadded 64 B (required
// by global_load_lds lane-linear dest; b128 reads at 64B stride hit the
// structural 8-cycle floor, no extra conflicts). Lean epilogue (no lora).
__global__ __launch_bounds__(256) void k_gemm(const int8_t* __restrict__ qx,
                                              const int8_t* __restrict__ qw,
                                              const float* __restrict__ sx,
                                              const float* __restrict__ sw,
                                              float* __restrict__ out) {
    __shared__ int8_t lsA[64 * 64];    // 4096 B
    __shared__ int8_t lsB[128 * 64];   // 8192 B
    int tid = threadIdx.x;
    int n0 = blockIdx.x * 128;
    int m0 = blockIdx.y * 64;
    int wid = tid >> 6, lane = tid & 63;
    int wr = wid >> 1, wc = wid & 1;
    int lg = lane >> 4, lr = lane & 15;

    // per-lane staging source pointers; wave-uniform LDS bases
    const int8_t* gA  = qx + (size_t)(m0 + wid * 16 + (lane >> 2)) * KPAD + (lane & 3) * 16;
    const int8_t* gB0 = qw + (size_t)(n0 + wid * 16 + (lane >> 2)) * KPAD + (lane & 3) * 16;
    const int8_t* gB1 = gB0 + (size_t)64 * KPAD;
    int8_t* lA  = &lsA[wid * 1024];
    int8_t* lB0 = &lsB[wid * 1024];
    int8_t* lB1 = &lsB[4096 + wid * 1024];

    vi4 acc[2][4];
    #pragma unroll
    for (int i = 0; i < 2; ++i)
        #pragma unroll
        for (int j = 0; j < 4; ++j) acc[i][j] = (vi4)0;

    for (int kk = 0; kk < KPAD; kk += 64) {
        async16(gA + kk, lA);
        async16(gB0 + kk, lB0);
        async16(gB1 + kk, lB1);
        __syncthreads();                 // vmcnt(0) drain before barrier covers the DMA
        vi4 af[2], bf[4];
        #pragma unroll
        for (int mi = 0; mi < 2; ++mi)
            af[mi] = *(vi4*)&lsA[(wr * 32 + mi * 16 + lr) * 64 + lg * 16];
        #pragma unroll
        for (int ni = 0; ni < 4; ++ni)
            bf[ni] = *(vi4*)&lsB[(wc * 64 + ni * 16 + lr) * 64 + lg * 16];
        #pragma unroll
        for (int mi = 0; mi < 2; ++mi)
            #pragma unroll
            for (int ni = 0; ni < 4; ++ni)
                acc[mi][ni] = __builtin_amdgcn_mfma_i32_16x16x64_i8(af[mi], bf[ni], acc[mi][ni], 0, 0, 0);
        __syncthreads();
    }

    float swv[4];
    #pragma unroll
    for (int ni = 0; ni < 4; ++ni) swv[ni] = sw[n0 + wc * 64 + ni * 16 + lr];
    #pragma unroll
    for (int mi = 0; mi < 2; ++mi) {
        int rbase = m0 + wr * 32 + mi * 16 + lg * 4;
        #pragma unroll
        for (int r = 0; r < 4; ++r) {
            int row = rbase + r;
            float sxv = sx[row];
            #pragma unroll
            for (int ni = 0; ni < 4; ++ni) {
                int col = n0 + wc * 64 + ni * 16 + lr;
                out[(size_t)row * OUT_F + col] = ((float)acc[mi][ni][r] * sxv) * swv[ni];
            }
        }
    }
}

// ---------------- epilogue: out += (sum_cc rpart) @ up + bias ----------------
__global__ __launch_bounds__(384) void k_epi(float* __restrict__ out,
                                             const __half* __restrict__ rpart,
                                             const float* __restrict__ up,
                                             const float* __restrict__ bias) {
    __shared__ float upl[RANK * OUT_F];   // 48 KB
    __shared__ float rs[32][RANK];        // 4 KB
    int tid = threadIdx.x;                // 0..383
    for (int i = tid; i < RANK * OUT_F; i += 384) upl[i] = up[i];
    int t0 = blockIdx.x * 32;
    for (int i = tid; i < 32 * RANK; i += 384) {
        int tt = i >> 5, j = i & 31;
        float s = 0.f;
        #pragma unroll
        for (int cc = 0; cc < NCH; ++cc)
            s += __half2float(rpart[((size_t)cc * NTOK + t0 + tt) * RANK + j]);
        rs[tt][j] = s;
    }
    __syncthreads();
    int o = tid;
    float b = bias[o];
    for (int tt = 0; tt < 32; ++tt) {
        int t = t0 + tt;
        float a = out[(size_t)t * OUT_F + o];
        float l = 0.f;
        #pragma unroll
        for (int j = 0; j < RANK; ++j) l = fmaf(rs[tt][j], upl[j * OUT_F + o], l);
        out[(size_t)t * OUT_F + o] = a + l + b;
    }
}

extern "C" void kernel_launch(void* const* d_in, const int* in_sizes, int n_in,
                              void* d_out, int out_size, void* d_ws, size_t ws_size,
                              hipStream_t stream) {
    const float* x    = (const float*)d_in[0];
    const float* w    = (const float*)d_in[1];
    const float* pd   = (const float*)d_in[2];
    const float* pu   = (const float*)d_in[3];
    const float* bias = (const float*)d_in[4];
    float* out = (float*)d_out;

    char* ws = (char*)d_ws;
    int8_t* qw    = (int8_t*)(ws + 0);           // 1,130,496
    float*  sw    = (float*) (ws + 1130496);     // 1,536
    float*  mb2   = (float*) (ws + 1132032);     // 8*16384*4 = 524,288
    float*  sx    = (float*) (ws + 1656320);     // 65,536
    int8_t* qx    = (int8_t*)(ws + 1721856);     // 48,234,496
    __half* rpart = (__half*)(ws + 49956352);    // 16*16384*32*2 = 16,777,216 (end 66,733,568)

    hipLaunchKernelGGL(kq_w,    dim3(OUT_F),    dim3(256), 0, stream, w, qw, sw);
    hipLaunchKernelGGL(k_chmax, dim3(64, 8),    dim3(256), 0, stream, x, mb2);
    hipLaunchKernelGGL(k_sx,    dim3(64),       dim3(256), 0, stream, mb2, sx);
    hipLaunchKernelGGL(k_fused, dim3(128, NCH), dim3(128), 0, stream, x, pd, sx, qx, rpart);
    hipLaunchKernelGGL(k_gemm,  dim3(3, 256),   dim3(256), 0, stream, qx, qw, sx, sw, out);
    hipLaunchKernelGGL(k_epi,   dim3(512),      dim3(384), 0, stream, out, rpart, pu, bias);
}

// Round 8
// 237.021 us; speedup vs baseline: 1.4761x; 1.0495x over previous
//
#include <hip/hip_runtime.h>
#include <hip/hip_fp16.h>
#include <stdint.h>
#include <stddef.h>

#define C_INC 320
#define KREAL 2880
#define KPAD  2944
#define OUT_F 384
#define RANK  32
#define HH    64
#define WW    64
#define NTOK  16384
#define NCH   16         // channel chunks for fused kernel
#define CCH   20         // channels per chunk (16*20=320)
#define QSTR  76         // qbuf row stride bytes (max 8ch*9=72 +4 pad)

typedef int vi4 __attribute__((ext_vector_type(4)));

// async global->LDS, 16B per lane; LDS dest is wave-uniform base + lane*16
static __device__ __forceinline__ void async16(const void* g, void* l) {
    __builtin_amdgcn_global_load_lds(
        (const __attribute__((address_space(1))) unsigned int*)g,
        (__attribute__((address_space(3))) unsigned int*)l, 16, 0, 0);
}

// ---------------- quantize weights per output row (exact IEEE div) ----------------
__global__ __launch_bounds__(256) void kq_w(const float* __restrict__ w,
                                            int8_t* __restrict__ qw,
                                            float* __restrict__ sw) {
    int o = blockIdx.x;
    const float* row = w + (size_t)o * KPAD;
    float m = 0.f;
    for (int k = threadIdx.x; k < KPAD; k += 256) m = fmaxf(m, fabsf(row[k]));
    #pragma unroll
    for (int off = 32; off > 0; off >>= 1) m = fmaxf(m, __shfl_down(m, off, 64));
    __shared__ float red[4];
    __shared__ float sval;
    if ((threadIdx.x & 63) == 0) red[threadIdx.x >> 6] = m;
    __syncthreads();
    if (threadIdx.x == 0) {
        float mm = fmaxf(fmaxf(red[0], red[1]), fmaxf(red[2], red[3]));
        sval = fmaxf(mm / 7.0f, 1e-8f);
        sw[o] = sval;
    }
    __syncthreads();
    float s = sval;
    for (int k = threadIdx.x; k < KPAD; k += 256) {
        float q = rintf(row[k] / s);          // IEEE div + RNE, matches np
        q = fminf(fmaxf(q, -8.f), 7.f);
        qw[(size_t)o * KPAD + k] = (int8_t)q;
    }
}

// ---------------- per-pixel channel abs-max, channel-split (512 blocks) ----------------
__global__ __launch_bounds__(256) void k_chmax(const float* __restrict__ x,
                                               float* __restrict__ mb2) {
    int p = blockIdx.x * 256 + threadIdx.x;   // 0..16383
    int cc = blockIdx.y;                       // 0..7
    int n = p >> 12, hw = p & 4095;
    const float* base = x + ((size_t)(n * C_INC) + cc * 40) * 4096 + hw;
    float m = 0.f;
    #pragma unroll 4
    for (int c = 0; c < 40; ++c) m = fmaxf(m, fabsf(base[(size_t)c * 4096]));
    mb2[(size_t)cc * NTOK + p] = m;
}

// ---------------- sx = max over 3x3 neighborhood of 8 planes / 7 ----------------
__global__ __launch_bounds__(256) void k_sx(const float* __restrict__ mb2,
                                            float* __restrict__ sx) {
    int p = blockIdx.x * 256 + threadIdx.x;
    int n = p >> 12, hw = p & 4095;
    int h = hw >> 6, w = hw & 63;
    float m = 0.f;
    #pragma unroll
    for (int cc = 0; cc < 8; ++cc) {
        const float* pl = mb2 + (size_t)cc * NTOK + (n << 12);
        #pragma unroll
        for (int di = -1; di <= 1; ++di)
            #pragma unroll
            for (int dj = -1; dj <= 1; ++dj) {
                int hh = h + di, ww = w + dj;
                if ((unsigned)hh < (unsigned)HH && (unsigned)ww < (unsigned)WW)
                    m = fmaxf(m, pl[(hh << 6) + ww]);
            }
    }
    sx[p] = fmaxf(m / 7.0f, 1e-8f);
}

// ---------------- fused im2col quantize + LoRA down-projection ----------------
// grid (64, 16), block 256 (R5 shape — 128-thr split regressed, R7). One wave
// per image row (lane = w). Per channel: 3 coalesced row loads; horizontal
// neighbors via UNCONDITIONAL shfl + select (shfl never sits in a divergent
// arm — that was R2's corruption). Next channel's rows software-prefetched.
__global__ __launch_bounds__(256) void k_fused(const float* __restrict__ x,
                                               const float* __restrict__ pd,
                                               const float* __restrict__ sx,
                                               int8_t* __restrict__ qx,
                                               __half* __restrict__ rpart) {
    __shared__ float  pdl[8 * 9 * RANK];   // 9216 B (max phase: 8 channels)
    __shared__ int8_t qbuf[256 * QSTR];    // 19456 B
    const int pstart[4] = {0, 8, 16, 20};  // phase channel starts (sizes 8,8,4)
    const int phoff[3]  = {0, 72, 144};    // byte offset within this chunk's k-range

    int tid = threadIdx.x;                 // 0..255
    int rg = blockIdx.x;                   // 0..63
    int cc = blockIdx.y;                   // 0..15
    int n = rg >> 4, h4 = rg & 15;
    int wid = tid >> 6, lane = tid & 63;
    int h = h4 * 4 + wid;
    int c0 = cc * CCH;

    int t = (n << 12) + (h << 6) + lane;
    float s = sx[t];
    float inv = 1.0f / s;                  // one exact div per lane
    const float* xrow = x + ((size_t)(n * C_INC) + c0) * 4096 + (h << 6) + lane;
    bool hok0 = (h > 0), hok2 = (h < 63);
    bool wok0 = (lane > 0), wok2 = (lane < 63);
    int bt = (n << 12) + (h4 << 8);        // block's first token

    float acc[RANK];
    #pragma unroll
    for (int j = 0; j < RANK; ++j) acc[j] = 0.f;

    for (int ph = 0; ph < 3; ++ph) {
        int ps = pstart[ph], pch = pstart[ph + 1] - ps;
        __syncthreads();   // prior phase's pdl reads + qbuf writes complete
        if (ph > 0) {      // flush previous phase (8 ch = 18 dwords/row)
            for (int i = tid; i < 256 * 18; i += 256) {
                int row = i / 18, col = i - row * 18;
                *(unsigned int*)&qx[(size_t)(bt + row) * KPAD + cc * 180 + phoff[ph - 1] + col * 4] =
                    *(unsigned int*)&qbuf[row * QSTR + col * 4];
            }
        }
        for (int i = tid; i < pch * 9 * RANK; i += 256)
            pdl[i] = pd[((size_t)(c0 + ps) * 9) * RANK + i];
        __syncthreads();   // pdl ready, flush done

        // initial row loads for this phase
        const float* xc0 = xrow + (size_t)ps * 4096;
        float r0 = hok0 ? xc0[-64] : 0.f;
        float r1 = xc0[0];
        float r2 = hok2 ? xc0[64] : 0.f;

        for (int cl = 0; cl < pch; ++cl) {
            // prefetch next channel's rows
            float p0 = 0.f, p1 = 0.f, p2 = 0.f;
            if (cl + 1 < pch) {
                const float* xn = xrow + (size_t)(ps + cl + 1) * 4096;
                p0 = hok0 ? xn[-64] : 0.f;
                p1 = xn[0];
                p2 = hok2 ? xn[64] : 0.f;
            }
            // horizontal neighbors: shfl executed by ALL lanes, then select
            float u0 = __shfl_up(r0, 1, 64), d0 = __shfl_down(r0, 1, 64);
            float u1 = __shfl_up(r1, 1, 64), d1 = __shfl_down(r1, 1, 64);
            float u2 = __shfl_up(r2, 1, 64), d2 = __shfl_down(r2, 1, 64);
            float v[9];
            v[0] = wok0 ? u0 : 0.f;  v[1] = r0;  v[2] = wok2 ? d0 : 0.f;
            v[3] = wok0 ? u1 : 0.f;  v[4] = r1;  v[5] = wok2 ? d1 : 0.f;
            v[6] = wok0 ? u2 : 0.f;  v[7] = r2;  v[8] = wok2 ? d2 : 0.f;
            #pragma unroll
            for (int u = 0; u < 9; ++u) {
                float q = rintf(v[u] * inv);
                q = fminf(fmaxf(q, -8.f), 7.f);
                qbuf[tid * QSTR + cl * 9 + u] = (int8_t)q;
                const float4* p4 = (const float4*)&pdl[(cl * 9 + u) * RANK];
                #pragma unroll
                for (int jj = 0; jj < 8; ++jj) {
                    float4 pv = p4[jj];
                    acc[jj * 4 + 0] = fmaf(v[u], pv.x, acc[jj * 4 + 0]);
                    acc[jj * 4 + 1] = fmaf(v[u], pv.y, acc[jj * 4 + 1]);
                    acc[jj * 4 + 2] = fmaf(v[u], pv.z, acc[jj * 4 + 2]);
                    acc[jj * 4 + 3] = fmaf(v[u], pv.w, acc[jj * 4 + 3]);
                }
            }
            r0 = p0; r1 = p1; r2 = p2;
        }
    }

    // store rpart partials as fp16
    {
        union { __half hh[RANK]; uint4 u4[4]; } pk;
        #pragma unroll
        for (int j = 0; j < RANK; ++j) pk.hh[j] = __float2half_rn(acc[j]);
        uint4* rp = (uint4*)(rpart + ((size_t)cc * NTOK + t) * RANK);
        rp[0] = pk.u4[0]; rp[1] = pk.u4[1]; rp[2] = pk.u4[2]; rp[3] = pk.u4[3];
    }

    // flush phase 2 (4 ch = 9 dwords; cc==15 adds 16 zero dwords for k-pad)
    __syncthreads();
    if (cc == NCH - 1) {
        for (int i = tid; i < 256 * 25; i += 256) {
            int row = i / 25, col = i - row * 25;
            unsigned int vdw = (col < 9) ? *(unsigned int*)&qbuf[row * QSTR + col * 4] : 0u;
            *(unsigned int*)&qx[(size_t)(bt + row) * KPAD + cc * 180 + 144 + col * 4] = vdw;
        }
    } else {
        for (int i = tid; i < 256 * 9; i += 256) {
            int row = i / 9, col = i - row * 9;
            *(unsigned int*)&qx[(size_t)(bt + row) * KPAD + cc * 180 + 144 + col * 4] =
                *(unsigned int*)&qbuf[row * QSTR + col * 4];
        }
    }
}

// ---------------- int8 MFMA GEMM: 64x128 tiles, async global->LDS staging (R7) ----------------
__global__ __launch_bounds__(256) void k_gemm(const int8_t* __restrict__ qx,
                                              const int8_t* __restrict__ qw,
                                              const float* __restrict__ sx,
                                              const float* __restrict__ sw,
                                              float* __restrict__ out) {
    __shared__ int8_t lsA[64 * 64];    // 4096 B
    __shared__ int8_t lsB[128 * 64];   // 8192 B
    int tid = threadIdx.x;
    int n0 = blockIdx.x * 128;
    int m0 = blockIdx.y * 64;
    int wid = tid >> 6, lane = tid & 63;
    int wr = wid >> 1, wc = wid & 1;
    int lg = lane >> 4, lr = lane & 15;

    const int8_t* gA  = qx + (size_t)(m0 + wid * 16 + (lane >> 2)) * KPAD + (lane & 3) * 16;
    const int8_t* gB0 = qw + (size_t)(n0 + wid * 16 + (lane >> 2)) * KPAD + (lane & 3) * 16;
    const int8_t* gB1 = gB0 + (size_t)64 * KPAD;
    int8_t* lA  = &lsA[wid * 1024];
    int8_t* lB0 = &lsB[wid * 1024];
    int8_t* lB1 = &lsB[4096 + wid * 1024];

    vi4 acc[2][4];
    #pragma unroll
    for (int i = 0; i < 2; ++i)
        #pragma unroll
        for (int j = 0; j < 4; ++j) acc[i][j] = (vi4)0;

    for (int kk = 0; kk < KPAD; kk += 64) {
        async16(gA + kk, lA);
        async16(gB0 + kk, lB0);
        async16(gB1 + kk, lB1);
        __syncthreads();
        vi4 af[2], bf[4];
        #pragma unroll
        for (int mi = 0; mi < 2; ++mi)
            af[mi] = *(vi4*)&lsA[(wr * 32 + mi * 16 + lr) * 64 + lg * 16];
        #pragma unroll
        for (int ni = 0; ni < 4; ++ni)
            bf[ni] = *(vi4*)&lsB[(wc * 64 + ni * 16 + lr) * 64 + lg * 16];
        #pragma unroll
        for (int mi = 0; mi < 2; ++mi)
            #pragma unroll
            for (int ni = 0; ni < 4; ++ni)
                acc[mi][ni] = __builtin_amdgcn_mfma_i32_16x16x64_i8(af[mi], bf[ni], acc[mi][ni], 0, 0, 0);
        __syncthreads();
    }

    float swv[4];
    #pragma unroll
    for (int ni = 0; ni < 4; ++ni) swv[ni] = sw[n0 + wc * 64 + ni * 16 + lr];
    #pragma unroll
    for (int mi = 0; mi < 2; ++mi) {
        int rbase = m0 + wr * 32 + mi * 16 + lg * 4;
        #pragma unroll
        for (int r = 0; r < 4; ++r) {
            int row = rbase + r;
            float sxv = sx[row];
            #pragma unroll
            for (int ni = 0; ni < 4; ++ni) {
                int col = n0 + wc * 64 + ni * 16 + lr;
                out[(size_t)row * OUT_F + col] = ((float)acc[mi][ni][r] * sxv) * swv[ni];
            }
        }
    }
}

// ---------------- epilogue: out += (sum_cc rpart) @ up + bias ----------------
__global__ __launch_bounds__(384) void k_epi(float* __restrict__ out,
                                             const __half* __restrict__ rpart,
                                             const float* __restrict__ up,
                                             const float* __restrict__ bias) {
    __shared__ float upl[RANK * OUT_F];   // 48 KB
    __shared__ float rs[32][RANK];        // 4 KB
    int tid = threadIdx.x;                // 0..383
    for (int i = tid; i < RANK * OUT_F; i += 384) upl[i] = up[i];
    int t0 = blockIdx.x * 32;
    for (int i = tid; i < 32 * RANK; i += 384) {
        int tt = i >> 5, j = i & 31;
        float s = 0.f;
        #pragma unroll
        for (int cc = 0; cc < NCH; ++cc)
            s += __half2float(rpart[((size_t)cc * NTOK + t0 + tt) * RANK + j]);
        rs[tt][j] = s;
    }
    __syncthreads();
    int o = tid;
    float b = bias[o];
    for (int tt = 0; tt < 32; ++tt) {
        int t = t0 + tt;
        float a = out[(size_t)t * OUT_F + o];
        float l = 0.f;
        #pragma unroll
        for (int j = 0; j < RANK; ++j) l = fmaf(rs[tt][j], upl[j * OUT_F + o], l);
        out[(size_t)t * OUT_F + o] = a + l + b;
    }
}

extern "C" void kernel_launch(void* const* d_in, const int* in_sizes, int n_in,
                              void* d_out, int out_size, void* d_ws, size_t ws_size,
                              hipStream_t stream) {
    const float* x    = (const float*)d_in[0];
    const float* w    = (const float*)d_in[1];
    const float* pd   = (const float*)d_in[2];
    const float* pu   = (const float*)d_in[3];
    const float* bias = (const float*)d_in[4];
    float* out = (float*)d_out;

    char* ws = (char*)d_ws;
    int8_t* qw    = (int8_t*)(ws + 0);           // 1,130,496
    float*  sw    = (float*) (ws + 1130496);     // 1,536
    float*  mb2   = (float*) (ws + 1132032);     // 8*16384*4 = 524,288
    float*  sx    = (float*) (ws + 1656320);     // 65,536
    int8_t* qx    = (int8_t*)(ws + 1721856);     // 48,234,496
    __half* rpart = (__half*)(ws + 49956352);    // 16*16384*32*2 = 16,777,216 (end 66,733,568)

    hipLaunchKernelGGL(kq_w,    dim3(OUT_F),    dim3(256), 0, stream, w, qw, sw);
    hipLaunchKernelGGL(k_chmax, dim3(64, 8),    dim3(256), 0, stream, x, mb2);
    hipLaunchKernelGGL(k_sx,    dim3(64),       dim3(256), 0, stream, mb2, sx);
    hipLaunchKernelGGL(k_fused, dim3(64, NCH),  dim3(256), 0, stream, x, pd, sx, qx, rpart);
    hipLaunchKernelGGL(k_gemm,  dim3(3, 256),   dim3(256), 0, stream, qx, qw, sx, sw, out);
    hipLaunchKernelGGL(k_epi,   dim3(512),      dim3(384), 0, stream, out, rpart, pu, bias);
}

// Round 9
// 228.974 us; speedup vs baseline: 1.5280x; 1.0351x over previous
//
#include <hip/hip_runtime.h>
#include <hip/hip_fp16.h>
#include <stdint.h>
#include <stddef.h>

#define C_INC 320
#define KREAL 2880
#define KPAD  2944
#define OUT_F 384
#define RANK  32
#define HH    64
#define WW    64
#define NTOK  16384
#define NCH   16         // channel chunks for fused kernel
#define CCH   20         // channels per chunk (16*20=320)
#define QSTR  76         // qbuf row stride bytes (max 8ch*9=72 +4 pad)

typedef int   vi4 __attribute__((ext_vector_type(4)));
typedef float v2f __attribute__((ext_vector_type(2)));

// async global->LDS, 16B per lane; LDS dest is wave-uniform base + lane*16
static __device__ __forceinline__ void async16(const void* g, void* l) {
    __builtin_amdgcn_global_load_lds(
        (const __attribute__((address_space(1))) unsigned int*)g,
        (__attribute__((address_space(3))) unsigned int*)l, 16, 0, 0);
}

// ---------------- quantize weights per output row (exact IEEE div) ----------------
__global__ __launch_bounds__(256) void kq_w(const float* __restrict__ w,
                                            int8_t* __restrict__ qw,
                                            float* __restrict__ sw) {
    int o = blockIdx.x;
    const float* row = w + (size_t)o * KPAD;
    float m = 0.f;
    for (int k = threadIdx.x; k < KPAD; k += 256) m = fmaxf(m, fabsf(row[k]));
    #pragma unroll
    for (int off = 32; off > 0; off >>= 1) m = fmaxf(m, __shfl_down(m, off, 64));
    __shared__ float red[4];
    __shared__ float sval;
    if ((threadIdx.x & 63) == 0) red[threadIdx.x >> 6] = m;
    __syncthreads();
    if (threadIdx.x == 0) {
        float mm = fmaxf(fmaxf(red[0], red[1]), fmaxf(red[2], red[3]));
        sval = fmaxf(mm / 7.0f, 1e-8f);
        sw[o] = sval;
    }
    __syncthreads();
    float s = sval;
    for (int k = threadIdx.x; k < KPAD; k += 256) {
        float q = rintf(row[k] / s);          // IEEE div + RNE, matches np
        q = fminf(fmaxf(q, -8.f), 7.f);
        qw[(size_t)o * KPAD + k] = (int8_t)q;
    }
}

// ---------------- per-pixel channel abs-max, channel-split (512 blocks) ----------------
__global__ __launch_bounds__(256) void k_chmax(const float* __restrict__ x,
                                               float* __restrict__ mb2) {
    int p = blockIdx.x * 256 + threadIdx.x;   // 0..16383
    int cc = blockIdx.y;                       // 0..7
    int n = p >> 12, hw = p & 4095;
    const float* base = x + ((size_t)(n * C_INC) + cc * 40) * 4096 + hw;
    float m = 0.f;
    #pragma unroll 4
    for (int c = 0; c < 40; ++c) m = fmaxf(m, fabsf(base[(size_t)c * 4096]));
    mb2[(size_t)cc * NTOK + p] = m;
}

// ---------------- sx = max over 3x3 neighborhood of 8 planes / 7 ----------------
__global__ __launch_bounds__(256) void k_sx(const float* __restrict__ mb2,
                                            float* __restrict__ sx) {
    int p = blockIdx.x * 256 + threadIdx.x;
    int n = p >> 12, hw = p & 4095;
    int h = hw >> 6, w = hw & 63;
    float m = 0.f;
    #pragma unroll
    for (int cc = 0; cc < 8; ++cc) {
        const float* pl = mb2 + (size_t)cc * NTOK + (n << 12);
        #pragma unroll
        for (int di = -1; di <= 1; ++di)
            #pragma unroll
            for (int dj = -1; dj <= 1; ++dj) {
                int hh = h + di, ww = w + dj;
                if ((unsigned)hh < (unsigned)HH && (unsigned)ww < (unsigned)WW)
                    m = fmaxf(m, pl[(hh << 6) + ww]);
            }
    }
    sx[p] = fmaxf(m / 7.0f, 1e-8f);
}

// ---------------- fused im2col quantize + LoRA down-projection ----------------
// grid (32, 16), block 256: each block covers 8 image rows (2 TOKENS PER
// THREAD: rows h0+wid and h0+4+wid) so the per-wave-uniform pd broadcast
// reads amortize over 2 tokens (halves DS-pipe cost/token). acc as float2 ->
// v_pk_fma_f32 halves VALU fma instrs. shfl always unconditional (R2/R4).
__global__ __launch_bounds__(256) void k_fused(const float* __restrict__ x,
                                               const float* __restrict__ pd,
                                               const float* __restrict__ sx,
                                               int8_t* __restrict__ qx,
                                               __half* __restrict__ rpart) {
    __shared__ float  pdl[8 * 9 * RANK];   // 9216 B (max phase: 8 channels)
    __shared__ int8_t qbuf[512 * QSTR];    // 38912 B (512 token rows)
    const int pstart[4] = {0, 8, 16, 20};  // phase channel starts (sizes 8,8,4)
    const int phoff[3]  = {0, 72, 144};    // byte offset within this chunk's k-range

    int tid = threadIdx.x;                 // 0..255
    int rg = blockIdx.x;                   // 0..31
    int cc = blockIdx.y;                   // 0..15
    int n = rg >> 3, h8 = rg & 7;
    int wid = tid >> 6, lane = tid & 63;
    int h0 = h8 * 8;
    int ha = h0 + wid, hb = h0 + 4 + wid;
    int c0 = cc * CCH;

    int ta = (n << 12) + (ha << 6) + lane;
    int tb = (n << 12) + (hb << 6) + lane;
    float inva = 1.0f / sx[ta];
    float invb = 1.0f / sx[tb];
    const float* xrowa = x + ((size_t)(n * C_INC) + c0) * 4096 + (ha << 6) + lane;
    const float* xrowb = x + ((size_t)(n * C_INC) + c0) * 4096 + (hb << 6) + lane;
    bool hok0a = (ha > 0), hok2a = (ha < 63);
    bool hok0b = (hb > 0), hok2b = (hb < 63);
    bool wok0 = (lane > 0), wok2 = (lane < 63);
    int bt = (n << 12) + (h8 << 9);        // block's first token (8 rows)
    int qra = wid * 64 + lane;             // qbuf row for token a
    int qrb = 256 + wid * 64 + lane;       // qbuf row for token b

    v2f acca[16], accb[16];
    #pragma unroll
    for (int j = 0; j < 16; ++j) { acca[j] = (v2f)0.f; accb[j] = (v2f)0.f; }

    for (int ph = 0; ph < 3; ++ph) {
        int ps = pstart[ph], pch = pstart[ph + 1] - ps;
        __syncthreads();   // prior phase's pdl reads + qbuf writes complete
        if (ph > 0) {      // flush previous phase (8 ch = 18 dwords/row, 512 rows)
            for (int i = tid; i < 512 * 18; i += 256) {
                int row = i / 18, col = i - row * 18;
                *(unsigned int*)&qx[(size_t)(bt + row) * KPAD + cc * 180 + phoff[ph - 1] + col * 4] =
                    *(unsigned int*)&qbuf[row * QSTR + col * 4];
            }
        }
        for (int i = tid; i < pch * 9 * RANK; i += 256)
            pdl[i] = pd[((size_t)(c0 + ps) * 9) * RANK + i];
        __syncthreads();   // pdl ready, flush done

        // initial row loads for this phase (both tokens)
        const float* xca = xrowa + (size_t)ps * 4096;
        const float* xcb = xrowb + (size_t)ps * 4096;
        float r0a = hok0a ? xca[-64] : 0.f, r1a = xca[0], r2a = hok2a ? xca[64] : 0.f;
        float r0b = hok0b ? xcb[-64] : 0.f, r1b = xcb[0], r2b = hok2b ? xcb[64] : 0.f;

        for (int cl = 0; cl < pch; ++cl) {
            // prefetch next channel's rows
            float p0a = 0.f, p1a = 0.f, p2a = 0.f, p0b = 0.f, p1b = 0.f, p2b = 0.f;
            if (cl + 1 < pch) {
                const float* xna = xrowa + (size_t)(ps + cl + 1) * 4096;
                const float* xnb = xrowb + (size_t)(ps + cl + 1) * 4096;
                p0a = hok0a ? xna[-64] : 0.f; p1a = xna[0]; p2a = hok2a ? xna[64] : 0.f;
                p0b = hok0b ? xnb[-64] : 0.f; p1b = xnb[0]; p2b = hok2b ? xnb[64] : 0.f;
            }
            // horizontal neighbors: shfl executed by ALL lanes, then select
            float va[9], vb[9];
            {
                float u0 = __shfl_up(r0a, 1, 64), d0 = __shfl_down(r0a, 1, 64);
                float u1 = __shfl_up(r1a, 1, 64), d1 = __shfl_down(r1a, 1, 64);
                float u2 = __shfl_up(r2a, 1, 64), d2 = __shfl_down(r2a, 1, 64);
                va[0] = wok0 ? u0 : 0.f; va[1] = r0a; va[2] = wok2 ? d0 : 0.f;
                va[3] = wok0 ? u1 : 0.f; va[4] = r1a; va[5] = wok2 ? d1 : 0.f;
                va[6] = wok0 ? u2 : 0.f; va[7] = r2a; va[8] = wok2 ? d2 : 0.f;
            }
            {
                float u0 = __shfl_up(r0b, 1, 64), d0 = __shfl_down(r0b, 1, 64);
                float u1 = __shfl_up(r1b, 1, 64), d1 = __shfl_down(r1b, 1, 64);
                float u2 = __shfl_up(r2b, 1, 64), d2 = __shfl_down(r2b, 1, 64);
                vb[0] = wok0 ? u0 : 0.f; vb[1] = r0b; vb[2] = wok2 ? d0 : 0.f;
                vb[3] = wok0 ? u1 : 0.f; vb[4] = r1b; vb[5] = wok2 ? d1 : 0.f;
                vb[6] = wok0 ? u2 : 0.f; vb[7] = r2b; vb[8] = wok2 ? d2 : 0.f;
            }
            #pragma unroll
            for (int u = 0; u < 9; ++u) {
                float qa = rintf(va[u] * inva);
                qa = fminf(fmaxf(qa, -8.f), 7.f);
                qbuf[qra * QSTR + cl * 9 + u] = (int8_t)qa;
                float qb = rintf(vb[u] * invb);
                qb = fminf(fmaxf(qb, -8.f), 7.f);
                qbuf[qrb * QSTR + cl * 9 + u] = (int8_t)qb;
                // pd fragment broadcast (wave-uniform) shared by both tokens
                const v2f* p2 = (const v2f*)&pdl[(cl * 9 + u) * RANK];
                v2f va2; va2[0] = va[u]; va2[1] = va[u];
                v2f vb2; vb2[0] = vb[u]; vb2[1] = vb[u];
                #pragma unroll
                for (int jj = 0; jj < 16; ++jj) {
                    v2f pv = p2[jj];
                    acca[jj] += pv * va2;   // v_pk_fma_f32
                    accb[jj] += pv * vb2;
                }
            }
            r0a = p0a; r1a = p1a; r2a = p2a;
            r0b = p0b; r1b = p1b; r2b = p2b;
        }
    }

    // store rpart partials as fp16 (both tokens)
    {
        union { __half hh[RANK]; uint4 u4[4]; } pk;
        #pragma unroll
        for (int j = 0; j < 16; ++j) {
            pk.hh[2 * j]     = __float2half_rn(acca[j][0]);
            pk.hh[2 * j + 1] = __float2half_rn(acca[j][1]);
        }
        uint4* rp = (uint4*)(rpart + ((size_t)cc * NTOK + ta) * RANK);
        rp[0] = pk.u4[0]; rp[1] = pk.u4[1]; rp[2] = pk.u4[2]; rp[3] = pk.u4[3];
        #pragma unroll
        for (int j = 0; j < 16; ++j) {
            pk.hh[2 * j]     = __float2half_rn(accb[j][0]);
            pk.hh[2 * j + 1] = __float2half_rn(accb[j][1]);
        }
        rp = (uint4*)(rpart + ((size_t)cc * NTOK + tb) * RANK);
        rp[0] = pk.u4[0]; rp[1] = pk.u4[1]; rp[2] = pk.u4[2]; rp[3] = pk.u4[3];
    }

    // flush phase 2 (4 ch = 9 dwords; cc==15 adds 16 zero dwords for k-pad)
    __syncthreads();
    if (cc == NCH - 1) {
        for (int i = tid; i < 512 * 25; i += 256) {
            int row = i / 25, col = i - row * 25;
            unsigned int vdw = (col < 9) ? *(unsigned int*)&qbuf[row * QSTR + col * 4] : 0u;
            *(unsigned int*)&qx[(size_t)(bt + row) * KPAD + cc * 180 + 144 + col * 4] = vdw;
        }
    } else {
        for (int i = tid; i < 512 * 9; i += 256) {
            int row = i / 9, col = i - row * 9;
            *(unsigned int*)&qx[(size_t)(bt + row) * KPAD + cc * 180 + 144 + col * 4] =
                *(unsigned int*)&qbuf[row * QSTR + col * 4];
        }
    }
}

// ---------------- int8 MFMA GEMM: 64x128 tiles, async global->LDS staging (R7) ----------------
__global__ __launch_bounds__(256) void k_gemm(const int8_t* __restrict__ qx,
                                              const int8_t* __restrict__ qw,
                                              const float* __restrict__ sx,
                                              const float* __restrict__ sw,
                                              float* __restrict__ out) {
    __shared__ int8_t lsA[64 * 64];    // 4096 B
    __shared__ int8_t lsB[128 * 64];   // 8192 B
    int tid = threadIdx.x;
    int n0 = blockIdx.x * 128;
    int m0 = blockIdx.y * 64;
    int wid = tid >> 6, lane = tid & 63;
    int wr = wid >> 1, wc = wid & 1;
    int lg = lane >> 4, lr = lane & 15;

    const int8_t* gA  = qx + (size_t)(m0 + wid * 16 + (lane >> 2)) * KPAD + (lane & 3) * 16;
    const int8_t* gB0 = qw + (size_t)(n0 + wid * 16 + (lane >> 2)) * KPAD + (lane & 3) * 16;
    const int8_t* gB1 = gB0 + (size_t)64 * KPAD;
    int8_t* lA  = &lsA[wid * 1024];
    int8_t* lB0 = &lsB[wid * 1024];
    int8_t* lB1 = &lsB[4096 + wid * 1024];

    vi4 acc[2][4];
    #pragma unroll
    for (int i = 0; i < 2; ++i)
        #pragma unroll
        for (int j = 0; j < 4; ++j) acc[i][j] = (vi4)0;

    for (int kk = 0; kk < KPAD; kk += 64) {
        async16(gA + kk, lA);
        async16(gB0 + kk, lB0);
        async16(gB1 + kk, lB1);
        __syncthreads();
        vi4 af[2], bf[4];
        #pragma unroll
        for (int mi = 0; mi < 2; ++mi)
            af[mi] = *(vi4*)&lsA[(wr * 32 + mi * 16 + lr) * 64 + lg * 16];
        #pragma unroll
        for (int ni = 0; ni < 4; ++ni)
            bf[ni] = *(vi4*)&lsB[(wc * 64 + ni * 16 + lr) * 64 + lg * 16];
        #pragma unroll
        for (int mi = 0; mi < 2; ++mi)
            #pragma unroll
            for (int ni = 0; ni < 4; ++ni)
                acc[mi][ni] = __builtin_amdgcn_mfma_i32_16x16x64_i8(af[mi], bf[ni], acc[mi][ni], 0, 0, 0);
        __syncthreads();
    }

    float swv[4];
    #pragma unroll
    for (int ni = 0; ni < 4; ++ni) swv[ni] = sw[n0 + wc * 64 + ni * 16 + lr];
    #pragma unroll
    for (int mi = 0; mi < 2; ++mi) {
        int rbase = m0 + wr * 32 + mi * 16 + lg * 4;
        #pragma unroll
        for (int r = 0; r < 4; ++r) {
            int row = rbase + r;
            float sxv = sx[row];
            #pragma unroll
            for (int ni = 0; ni < 4; ++ni) {
                int col = n0 + wc * 64 + ni * 16 + lr;
                out[(size_t)row * OUT_F + col] = ((float)acc[mi][ni][r] * sxv) * swv[ni];
            }
        }
    }
}

// ---------------- epilogue: out += (sum_cc rpart) @ up + bias ----------------
__global__ __launch_bounds__(384) void k_epi(float* __restrict__ out,
                                             const __half* __restrict__ rpart,
                                             const float* __restrict__ up,
                                             const float* __restrict__ bias) {
    __shared__ float upl[RANK * OUT_F];   // 48 KB
    __shared__ float rs[32][RANK];        // 4 KB
    int tid = threadIdx.x;                // 0..383
    for (int i = tid; i < RANK * OUT_F; i += 384) upl[i] = up[i];
    int t0 = blockIdx.x * 32;
    for (int i = tid; i < 32 * RANK; i += 384) {
        int tt = i >> 5, j = i & 31;
        float s = 0.f;
        #pragma unroll
        for (int cc = 0; cc < NCH; ++cc)
            s += __half2float(rpart[((size_t)cc * NTOK + t0 + tt) * RANK + j]);
        rs[tt][j] = s;
    }
    __syncthreads();
    int o = tid;
    float b = bias[o];
    for (int tt = 0; tt < 32; ++tt) {
        int t = t0 + tt;
        float a = out[(size_t)t * OUT_F + o];
        float l = 0.f;
        #pragma unroll
        for (int j = 0; j < RANK; ++j) l = fmaf(rs[tt][j], upl[j * OUT_F + o], l);
        out[(size_t)t * OUT_F + o] = a + l + b;
    }
}

extern "C" void kernel_launch(void* const* d_in, const int* in_sizes, int n_in,
                              void* d_out, int out_size, void* d_ws, size_t ws_size,
                              hipStream_t stream) {
    const float* x    = (const float*)d_in[0];
    const float* w    = (const float*)d_in[1];
    const float* pd   = (const float*)d_in[2];
    const float* pu   = (const float*)d_in[3];
    const float* bias = (const float*)d_in[4];
    float* out = (float*)d_out;

    char* ws = (char*)d_ws;
    int8_t* qw    = (int8_t*)(ws + 0);           // 1,130,496
    float*  sw    = (float*) (ws + 1130496);     // 1,536
    float*  mb2   = (float*) (ws + 1132032);     // 8*16384*4 = 524,288
    float*  sx    = (float*) (ws + 1656320);     // 65,536
    int8_t* qx    = (int8_t*)(ws + 1721856);     // 48,234,496
    __half* rpart = (__half*)(ws + 49956352);    // 16*16384*32*2 = 16,777,216 (end 66,733,568)

    hipLaunchKernelGGL(kq_w,    dim3(OUT_F),    dim3(256), 0, stream, w, qw, sw);
    hipLaunchKernelGGL(k_chmax, dim3(64, 8),    dim3(256), 0, stream, x, mb2);
    hipLaunchKernelGGL(k_sx,    dim3(64),       dim3(256), 0, stream, mb2, sx);
    hipLaunchKernelGGL(k_fused, dim3(32, NCH),  dim3(256), 0, stream, x, pd, sx, qx, rpart);
    hipLaunchKernelGGL(k_gemm,  dim3(3, 256),   dim3(256), 0, stream, qx, qw, sx, sw, out);
    hipLaunchKernelGGL(k_epi,   dim3(512),      dim3(384), 0, stream, out, rpart, pu, bias);
}

// Round 10
// 226.694 us; speedup vs baseline: 1.5434x; 1.0101x over previous
//
#include <hip/hip_runtime.h>
#include <hip/hip_fp16.h>
#include <stdint.h>
#include <stddef.h>

#define C_INC 320
#define KREAL 2880
#define KPAD  2944
#define OUT_F 384
#define RANK  32
#define HH    64
#define WW    64
#define NTOK  16384
#define NCH   16         // channel chunks for fused kernel
#define CCH   20         // channels per chunk (16*20=320)
#define QSTR  76         // qbuf row stride bytes (max 8ch*9=72 +4 pad)

typedef int   vi4 __attribute__((ext_vector_type(4)));
typedef float v4f __attribute__((ext_vector_type(4)));

// async global->LDS, 16B per lane; LDS dest is wave-uniform base + lane*16
static __device__ __forceinline__ void async16(const void* g, void* l) {
    __builtin_amdgcn_global_load_lds(
        (const __attribute__((address_space(1))) unsigned int*)g,
        (__attribute__((address_space(3))) unsigned int*)l, 16, 0, 0);
}

// ---------------- quantize weights per output row (exact IEEE div) ----------------
__global__ __launch_bounds__(256) void kq_w(const float* __restrict__ w,
                                            int8_t* __restrict__ qw,
                                            float* __restrict__ sw) {
    int o = blockIdx.x;
    const float* row = w + (size_t)o * KPAD;
    float m = 0.f;
    for (int k = threadIdx.x; k < KPAD; k += 256) m = fmaxf(m, fabsf(row[k]));
    #pragma unroll
    for (int off = 32; off > 0; off >>= 1) m = fmaxf(m, __shfl_down(m, off, 64));
    __shared__ float red[4];
    __shared__ float sval;
    if ((threadIdx.x & 63) == 0) red[threadIdx.x >> 6] = m;
    __syncthreads();
    if (threadIdx.x == 0) {
        float mm = fmaxf(fmaxf(red[0], red[1]), fmaxf(red[2], red[3]));
        sval = fmaxf(mm / 7.0f, 1e-8f);
        sw[o] = sval;
    }
    __syncthreads();
    float s = sval;
    for (int k = threadIdx.x; k < KPAD; k += 256) {
        float q = rintf(row[k] / s);          // IEEE div + RNE, matches np
        q = fminf(fmaxf(q, -8.f), 7.f);
        qw[(size_t)o * KPAD + k] = (int8_t)q;
    }
}

// ---------------- per-pixel channel abs-max, channel-split (512 blocks) ----------------
__global__ __launch_bounds__(256) void k_chmax(const float* __restrict__ x,
                                               float* __restrict__ mb2) {
    int p = blockIdx.x * 256 + threadIdx.x;   // 0..16383
    int cc = blockIdx.y;                       // 0..7
    int n = p >> 12, hw = p & 4095;
    const float* base = x + ((size_t)(n * C_INC) + cc * 40) * 4096 + hw;
    float m = 0.f;
    #pragma unroll 4
    for (int c = 0; c < 40; ++c) m = fmaxf(m, fabsf(base[(size_t)c * 4096]));
    mb2[(size_t)cc * NTOK + p] = m;
}

// ---------------- sx = max over 3x3 neighborhood of 8 planes / 7 ----------------
__global__ __launch_bounds__(256) void k_sx(const float* __restrict__ mb2,
                                            float* __restrict__ sx) {
    int p = blockIdx.x * 256 + threadIdx.x;
    int n = p >> 12, hw = p & 4095;
    int h = hw >> 6, w = hw & 63;
    float m = 0.f;
    #pragma unroll
    for (int cc = 0; cc < 8; ++cc) {
        const float* pl = mb2 + (size_t)cc * NTOK + (n << 12);
        #pragma unroll
        for (int di = -1; di <= 1; ++di)
            #pragma unroll
            for (int dj = -1; dj <= 1; ++dj) {
                int hh = h + di, ww = w + dj;
                if ((unsigned)hh < (unsigned)HH && (unsigned)ww < (unsigned)WW)
                    m = fmaxf(m, pl[(hh << 6) + ww]);
            }
    }
    sx[p] = fmaxf(m / 7.0f, 1e-8f);
}

// ---------------- fused im2col quantize + LoRA down-projection ----------------
// grid (32, 16), block 256: 8 image rows, 2 tokens/thread (pd broadcasts
// amortized). pdl fragment reads widened to float4 (ds_read_b128, half the
// DS-pipe issues vs v2f; float4 arithmetic still lowers to v_pk_fma_f32,
// per-component order identical -> bit-identical results).
__global__ __launch_bounds__(256) void k_fused(const float* __restrict__ x,
                                               const float* __restrict__ pd,
                                               const float* __restrict__ sx,
                                               int8_t* __restrict__ qx,
                                               __half* __restrict__ rpart) {
    __shared__ float  pdl[8 * 9 * RANK];   // 9216 B (max phase: 8 channels)
    __shared__ int8_t qbuf[512 * QSTR];    // 38912 B (512 token rows)
    const int pstart[4] = {0, 8, 16, 20};  // phase channel starts (sizes 8,8,4)
    const int phoff[3]  = {0, 72, 144};    // byte offset within this chunk's k-range

    int tid = threadIdx.x;                 // 0..255
    int rg = blockIdx.x;                   // 0..31
    int cc = blockIdx.y;                   // 0..15
    int n = rg >> 3, h8 = rg & 7;
    int wid = tid >> 6, lane = tid & 63;
    int h0 = h8 * 8;
    int ha = h0 + wid, hb = h0 + 4 + wid;
    int c0 = cc * CCH;

    int ta = (n << 12) + (ha << 6) + lane;
    int tb = (n << 12) + (hb << 6) + lane;
    float inva = 1.0f / sx[ta];
    float invb = 1.0f / sx[tb];
    const float* xrowa = x + ((size_t)(n * C_INC) + c0) * 4096 + (ha << 6) + lane;
    const float* xrowb = x + ((size_t)(n * C_INC) + c0) * 4096 + (hb << 6) + lane;
    bool hok0a = (ha > 0), hok2a = (ha < 63);
    bool hok0b = (hb > 0), hok2b = (hb < 63);
    bool wok0 = (lane > 0), wok2 = (lane < 63);
    int bt = (n << 12) + (h8 << 9);        // block's first token (8 rows)
    int qra = wid * 64 + lane;             // qbuf row for token a
    int qrb = 256 + wid * 64 + lane;       // qbuf row for token b

    v4f acca[8], accb[8];
    #pragma unroll
    for (int j = 0; j < 8; ++j) { acca[j] = (v4f)0.f; accb[j] = (v4f)0.f; }

    for (int ph = 0; ph < 3; ++ph) {
        int ps = pstart[ph], pch = pstart[ph + 1] - ps;
        __syncthreads();   // prior phase's pdl reads + qbuf writes complete
        if (ph > 0) {      // flush previous phase (8 ch = 18 dwords/row, 512 rows)
            for (int i = tid; i < 512 * 18; i += 256) {
                int row = i / 18, col = i - row * 18;
                *(unsigned int*)&qx[(size_t)(bt + row) * KPAD + cc * 180 + phoff[ph - 1] + col * 4] =
                    *(unsigned int*)&qbuf[row * QSTR + col * 4];
            }
        }
        for (int i = tid; i < pch * 9 * RANK; i += 256)
            pdl[i] = pd[((size_t)(c0 + ps) * 9) * RANK + i];
        __syncthreads();   // pdl ready, flush done

        // initial row loads for this phase (both tokens)
        const float* xca = xrowa + (size_t)ps * 4096;
        const float* xcb = xrowb + (size_t)ps * 4096;
        float r0a = hok0a ? xca[-64] : 0.f, r1a = xca[0], r2a = hok2a ? xca[64] : 0.f;
        float r0b = hok0b ? xcb[-64] : 0.f, r1b = xcb[0], r2b = hok2b ? xcb[64] : 0.f;

        for (int cl = 0; cl < pch; ++cl) {
            // prefetch next channel's rows
            float p0a = 0.f, p1a = 0.f, p2a = 0.f, p0b = 0.f, p1b = 0.f, p2b = 0.f;
            if (cl + 1 < pch) {
                const float* xna = xrowa + (size_t)(ps + cl + 1) * 4096;
                const float* xnb = xrowb + (size_t)(ps + cl + 1) * 4096;
                p0a = hok0a ? xna[-64] : 0.f; p1a = xna[0]; p2a = hok2a ? xna[64] : 0.f;
                p0b = hok0b ? xnb[-64] : 0.f; p1b = xnb[0]; p2b = hok2b ? xnb[64] : 0.f;
            }
            // horizontal neighbors: shfl executed by ALL lanes, then select
            float va[9], vb[9];
            {
                float u0 = __shfl_up(r0a, 1, 64), d0 = __shfl_down(r0a, 1, 64);
                float u1 = __shfl_up(r1a, 1, 64), d1 = __shfl_down(r1a, 1, 64);
                float u2 = __shfl_up(r2a, 1, 64), d2 = __shfl_down(r2a, 1, 64);
                va[0] = wok0 ? u0 : 0.f; va[1] = r0a; va[2] = wok2 ? d0 : 0.f;
                va[3] = wok0 ? u1 : 0.f; va[4] = r1a; va[5] = wok2 ? d1 : 0.f;
                va[6] = wok0 ? u2 : 0.f; va[7] = r2a; va[8] = wok2 ? d2 : 0.f;
            }
            {
                float u0 = __shfl_up(r0b, 1, 64), d0 = __shfl_down(r0b, 1, 64);
                float u1 = __shfl_up(r1b, 1, 64), d1 = __shfl_down(r1b, 1, 64);
                float u2 = __shfl_up(r2b, 1, 64), d2 = __shfl_down(r2b, 1, 64);
                vb[0] = wok0 ? u0 : 0.f; vb[1] = r0b; vb[2] = wok2 ? d0 : 0.f;
                vb[3] = wok0 ? u1 : 0.f; vb[4] = r1b; vb[5] = wok2 ? d1 : 0.f;
                vb[6] = wok0 ? u2 : 0.f; vb[7] = r2b; vb[8] = wok2 ? d2 : 0.f;
            }
            #pragma unroll
            for (int u = 0; u < 9; ++u) {
                float qa = rintf(va[u] * inva);
                qa = fminf(fmaxf(qa, -8.f), 7.f);
                qbuf[qra * QSTR + cl * 9 + u] = (int8_t)qa;
                float qb = rintf(vb[u] * invb);
                qb = fminf(fmaxf(qb, -8.f), 7.f);
                qbuf[qrb * QSTR + cl * 9 + u] = (int8_t)qb;
                // pd fragment broadcast (wave-uniform) shared by both tokens
                const v4f* p4 = (const v4f*)&pdl[(cl * 9 + u) * RANK];
                v4f va4; va4[0] = va[u]; va4[1] = va[u]; va4[2] = va[u]; va4[3] = va[u];
                v4f vb4; vb4[0] = vb[u]; vb4[1] = vb[u]; vb4[2] = vb[u]; vb4[3] = vb[u];
                #pragma unroll
                for (int jj = 0; jj < 8; ++jj) {
                    v4f pv = p4[jj];
                    acca[jj] += pv * va4;   // 2x v_pk_fma_f32
                    accb[jj] += pv * vb4;
                }
            }
            r0a = p0a; r1a = p1a; r2a = p2a;
            r0b = p0b; r1b = p1b; r2b = p2b;
        }
    }

    // store rpart partials as fp16 (both tokens); rank index = 4*jj + c
    {
        union { __half hh[RANK]; uint4 u4[4]; } pk;
        #pragma unroll
        for (int jj = 0; jj < 8; ++jj) {
            pk.hh[4 * jj + 0] = __float2half_rn(acca[jj][0]);
            pk.hh[4 * jj + 1] = __float2half_rn(acca[jj][1]);
            pk.hh[4 * jj + 2] = __float2half_rn(acca[jj][2]);
            pk.hh[4 * jj + 3] = __float2half_rn(acca[jj][3]);
        }
        uint4* rp = (uint4*)(rpart + ((size_t)cc * NTOK + ta) * RANK);
        rp[0] = pk.u4[0]; rp[1] = pk.u4[1]; rp[2] = pk.u4[2]; rp[3] = pk.u4[3];
        #pragma unroll
        for (int jj = 0; jj < 8; ++jj) {
            pk.hh[4 * jj + 0] = __float2half_rn(accb[jj][0]);
            pk.hh[4 * jj + 1] = __float2half_rn(accb[jj][1]);
            pk.hh[4 * jj + 2] = __float2half_rn(accb[jj][2]);
            pk.hh[4 * jj + 3] = __float2half_rn(accb[jj][3]);
        }
        rp = (uint4*)(rpart + ((size_t)cc * NTOK + tb) * RANK);
        rp[0] = pk.u4[0]; rp[1] = pk.u4[1]; rp[2] = pk.u4[2]; rp[3] = pk.u4[3];
    }

    // flush phase 2 (4 ch = 9 dwords; cc==15 adds 16 zero dwords for k-pad)
    __syncthreads();
    if (cc == NCH - 1) {
        for (int i = tid; i < 512 * 25; i += 256) {
            int row = i / 25, col = i - row * 25;
            unsigned int vdw = (col < 9) ? *(unsigned int*)&qbuf[row * QSTR + col * 4] : 0u;
            *(unsigned int*)&qx[(size_t)(bt + row) * KPAD + cc * 180 + 144 + col * 4] = vdw;
        }
    } else {
        for (int i = tid; i < 512 * 9; i += 256) {
            int row = i / 9, col = i - row * 9;
            *(unsigned int*)&qx[(size_t)(bt + row) * KPAD + cc * 180 + 144 + col * 4] =
                *(unsigned int*)&qbuf[row * QSTR + col * 4];
        }
    }
}

// ---------------- int8 MFMA GEMM: 64x128 tiles, double-buffered async staging ----------------
// One barrier per K-iter: prefetch for tile k+1 is issued right after the
// barrier, then 8 MFMAs on tile k overlap the in-flight DMA before the next
// barrier's vmcnt drain (R7 had stage->barrier->compute->barrier: no overlap).
__global__ __launch_bounds__(256) void k_gemm(const int8_t* __restrict__ qx,
                                              const int8_t* __restrict__ qw,
                                              const float* __restrict__ sx,
                                              const float* __restrict__ sw,
                                              float* __restrict__ out) {
    __shared__ int8_t lsA[2][64 * 64];    // 2 x 4096 B
    __shared__ int8_t lsB[2][128 * 64];   // 2 x 8192 B
    int tid = threadIdx.x;
    int n0 = blockIdx.x * 128;
    int m0 = blockIdx.y * 64;
    int wid = tid >> 6, lane = tid & 63;
    int wr = wid >> 1, wc = wid & 1;
    int lg = lane >> 4, lr = lane & 15;

    const int8_t* gA  = qx + (size_t)(m0 + wid * 16 + (lane >> 2)) * KPAD + (lane & 3) * 16;
    const int8_t* gB0 = qw + (size_t)(n0 + wid * 16 + (lane >> 2)) * KPAD + (lane & 3) * 16;
    const int8_t* gB1 = gB0 + (size_t)64 * KPAD;
    int lofs = wid * 1024;

    vi4 acc[2][4];
    #pragma unroll
    for (int i = 0; i < 2; ++i)
        #pragma unroll
        for (int j = 0; j < 4; ++j) acc[i][j] = (vi4)0;

    // prologue: stage tile 0 into buffer 0
    async16(gA, &lsA[0][lofs]);
    async16(gB0, &lsB[0][lofs]);
    async16(gB1, &lsB[0][4096 + lofs]);
    __syncthreads();

    int cur = 0;
    for (int kk = 64; kk < KPAD; kk += 64) {
        int nxt = cur ^ 1;
        async16(gA + kk, &lsA[nxt][lofs]);
        async16(gB0 + kk, &lsB[nxt][lofs]);
        async16(gB1 + kk, &lsB[nxt][4096 + lofs]);
        // compute on current buffer while DMA is in flight
        vi4 af[2], bf[4];
        #pragma unroll
        for (int mi = 0; mi < 2; ++mi)
            af[mi] = *(vi4*)&lsA[cur][(wr * 32 + mi * 16 + lr) * 64 + lg * 16];
        #pragma unroll
        for (int ni = 0; ni < 4; ++ni)
            bf[ni] = *(vi4*)&lsB[cur][(wc * 64 + ni * 16 + lr) * 64 + lg * 16];
        #pragma unroll
        for (int mi = 0; mi < 2; ++mi)
            #pragma unroll
            for (int ni = 0; ni < 4; ++ni)
                acc[mi][ni] = __builtin_amdgcn_mfma_i32_16x16x64_i8(af[mi], bf[ni], acc[mi][ni], 0, 0, 0);
        __syncthreads();   // drains nxt staging; guards cur reuse next iter
        cur = nxt;
    }
    // last tile
    {
        vi4 af[2], bf[4];
        #pragma unroll
        for (int mi = 0; mi < 2; ++mi)
            af[mi] = *(vi4*)&lsA[cur][(wr * 32 + mi * 16 + lr) * 64 + lg * 16];
        #pragma unroll
        for (int ni = 0; ni < 4; ++ni)
            bf[ni] = *(vi4*)&lsB[cur][(wc * 64 + ni * 16 + lr) * 64 + lg * 16];
        #pragma unroll
        for (int mi = 0; mi < 2; ++mi)
            #pragma unroll
            for (int ni = 0; ni < 4; ++ni)
                acc[mi][ni] = __builtin_amdgcn_mfma_i32_16x16x64_i8(af[mi], bf[ni], acc[mi][ni], 0, 0, 0);
    }

    float swv[4];
    #pragma unroll
    for (int ni = 0; ni < 4; ++ni) swv[ni] = sw[n0 + wc * 64 + ni * 16 + lr];
    #pragma unroll
    for (int mi = 0; mi < 2; ++mi) {
        int rbase = m0 + wr * 32 + mi * 16 + lg * 4;
        #pragma unroll
        for (int r = 0; r < 4; ++r) {
            int row = rbase + r;
            float sxv = sx[row];
            #pragma unroll
            for (int ni = 0; ni < 4; ++ni) {
                int col = n0 + wc * 64 + ni * 16 + lr;
                out[(size_t)row * OUT_F + col] = ((float)acc[mi][ni][r] * sxv) * swv[ni];
            }
        }
    }
}

// ---------------- epilogue: out += (sum_cc rpart) @ up + bias ----------------
// up column held in 32 registers per thread (no 48 KB LDS stage); rs read as
// broadcast float4 (b128). Same j-ascending fma order -> bit-identical.
__global__ __launch_bounds__(384) void k_epi(float* __restrict__ out,
                                             const __half* __restrict__ rpart,
                                             const float* __restrict__ up,
                                             const float* __restrict__ bias) {
    __shared__ float rs[32][RANK];        // 4 KB
    int tid = threadIdx.x;                // 0..383
    int o = tid;
    float uc[RANK];
    #pragma unroll
    for (int j = 0; j < RANK; ++j) uc[j] = up[(size_t)j * OUT_F + o];
    float b = bias[o];
    int t0 = blockIdx.x * 32;
    for (int i = tid; i < 32 * RANK; i += 384) {
        int tt = i >> 5, j = i & 31;
        float s = 0.f;
        #pragma unroll
        for (int cc = 0; cc < NCH; ++cc)
            s += __half2float(rpart[((size_t)cc * NTOK + t0 + tt) * RANK + j]);
        rs[tt][j] = s;
    }
    __syncthreads();
    for (int tt = 0; tt < 32; ++tt) {
        int t = t0 + tt;
        float a = out[(size_t)t * OUT_F + o];
        float l = 0.f;
        const v4f* rv = (const v4f*)&rs[tt][0];
        #pragma unroll
        for (int j4 = 0; j4 < 8; ++j4) {
            v4f r4 = rv[j4];
            l = fmaf(r4[0], uc[4 * j4 + 0], l);
            l = fmaf(r4[1], uc[4 * j4 + 1], l);
            l = fmaf(r4[2], uc[4 * j4 + 2], l);
            l = fmaf(r4[3], uc[4 * j4 + 3], l);
        }
        out[(size_t)t * OUT_F + o] = a + l + b;
    }
}

extern "C" void kernel_launch(void* const* d_in, const int* in_sizes, int n_in,
                              void* d_out, int out_size, void* d_ws, size_t ws_size,
                              hipStream_t stream) {
    const float* x    = (const float*)d_in[0];
    const float* w    = (const float*)d_in[1];
    const float* pd   = (const float*)d_in[2];
    const float* pu   = (const float*)d_in[3];
    const float* bias = (const float*)d_in[4];
    float* out = (float*)d_out;

    char* ws = (char*)d_ws;
    int8_t* qw    = (int8_t*)(ws + 0);           // 1,130,496
    float*  sw    = (float*) (ws + 1130496);     // 1,536
    float*  mb2   = (float*) (ws + 1132032);     // 8*16384*4 = 524,288
    float*  sx    = (float*) (ws + 1656320);     // 65,536
    int8_t* qx    = (int8_t*)(ws + 1721856);     // 48,234,496
    __half* rpart = (__half*)(ws + 49956352);    // 16*16384*32*2 = 16,777,216 (end 66,733,568)

    hipLaunchKernelGGL(kq_w,    dim3(OUT_F),    dim3(256), 0, stream, w, qw, sw);
    hipLaunchKernelGGL(k_chmax, dim3(64, 8),    dim3(256), 0, stream, x, mb2);
    hipLaunchKernelGGL(k_sx,    dim3(64),       dim3(256), 0, stream, mb2, sx);
    hipLaunchKernelGGL(k_fused, dim3(32, NCH),  dim3(256), 0, stream, x, pd, sx, qx, rpart);
    hipLaunchKernelGGL(k_gemm,  dim3(3, 256),   dim3(256), 0, stream, qx, qw, sx, sw, out);
    hipLaunchKernelGGL(k_epi,   dim3(512),      dim3(384), 0, stream, out, rpart, pu, bias);
}